// Round 5
// baseline (202.909 us; speedup 1.0000x reference)
//
#include <hip/hip_runtime.h>

// RBF classifier: out = exp(-(||x-c||^2) * exp(-2*log_sigma)) @ W^T + b
// B=16384, D=784, C=2048, OUT=10. All fp32 in/out.
//
// R5: ZERO barriers in the K-loop. Both A (x) and B (centres) pre-packed in
// MFMA fragment order; each wave streams operands global->VGPR with manual
// 1-iter-ahead prefetch => compiler emits fine-grained s_waitcnt vmcnt(8)
// (AITER pattern), no synchronized vmcnt(0) drains (the 74-76us plateau of
// R2-R4). Tile 64x256, 4 waves of 64x64. LDS only for the phi epilogue.

#define B_ROWS 16384
#define D_DIM  784
#define C_DIM  2048
#define NOUT   10
#define NKC    26             // k-chunks of 32 (K padded 784->832)
#define NCG    128            // B col-groups of 16
#define NRG    1024           // A row-groups of 16
#define LOG2E  1.4426950408889634f

typedef __attribute__((ext_vector_type(8))) __bf16 bf16x8;
typedef __attribute__((ext_vector_type(4))) float  f32x4;

__device__ __forceinline__ unsigned short f2bf(float f) {
  union { float f; unsigned int u; } v; v.f = f;
  unsigned int u = v.u;
  return (unsigned short)((u + 0x7fffu + ((u >> 16) & 1u)) >> 16);  // RNE
}
__device__ __forceinline__ bf16x8 cvt8(float4 a, float4 b) {
  union { bf16x8 v; unsigned short s[8]; } o;
  o.s[0] = f2bf(a.x); o.s[1] = f2bf(a.y); o.s[2] = f2bf(a.z); o.s[3] = f2bf(a.w);
  o.s[4] = f2bf(b.x); o.s[5] = f2bf(b.y); o.s[6] = f2bf(b.z); o.s[7] = f2bf(b.w);
  return o.v;
}

// --- pack a (rows,784) fp32 matrix into MFMA A/B fragment tiles:
// tile t = kc*tiles_per_k + g; lane (q=lane>>4, l16) holds
// M[row=g*16+l16][k=kc*32+q*8+j], j=0..7 (16B/lane, 1KB/tile). Also emits
// per-row squared norms. One wave per group g, looping all kc (no atomics).
// For A: tile index = g*NKC + kc (kc contiguous per row-group).
// For B: tile index = kc*NCG + g (col-groups contiguous per kc).
template <int ROWS, int A_ORDER>
__global__ __launch_bounds__(256) void prep_pack(const float* __restrict__ src,
                                                 bf16x8* __restrict__ dst,
                                                 float* __restrict__ sq) {
  const int g    = blockIdx.x * 4 + (threadIdx.x >> 6);   // row/col group
  const int lane = threadIdx.x & 63;
  const int q    = lane >> 4;
  const int l16  = lane & 15;
  const int row  = g * 16 + l16;
  const float* s = src + (size_t)row * D_DIM;
  float acc = 0.f;
#pragma unroll 2
  for (int kc = 0; kc < NKC; ++kc) {
    const int k = kc * 32 + q * 8;
    bf16x8 o = {};
    if (k + 8 <= D_DIM) {   // 784 % 8 == 0: chunk fully valid or fully pad
      const float4 v0 = *(const float4*)(s + k);
      const float4 v1 = *(const float4*)(s + k + 4);
      o = cvt8(v0, v1);
      acc += v0.x * v0.x + v0.y * v0.y + v0.z * v0.z + v0.w * v0.w +
             v1.x * v1.x + v1.y * v1.y + v1.z * v1.z + v1.w * v1.w;
    }
    const size_t tile = A_ORDER ? ((size_t)g * NKC + kc)
                                : ((size_t)kc * (ROWS / 16) + g);
    dst[tile * 64 + lane] = o;
  }
  acc += __shfl_down(acc, 32);
  acc += __shfl_down(acc, 16);
  if (lane < 16 && row < ROWS) sq[row] = acc;
}

// fused tiny preps: out=bias | Wb bf16 (16,2048; rows 10..15 zero) | scale
// (pre-multiplied by log2(e) so epilogue uses exp2).
__global__ __launch_bounds__(256) void prep_misc(const float* __restrict__ ls,
                                                 const float* __restrict__ W,
                                                 const float* __restrict__ bias,
                                                 float* __restrict__ scale,
                                                 unsigned short* __restrict__ wb,
                                                 float* __restrict__ out) {
  const int i = blockIdx.x * 256 + threadIdx.x;
  if (i < B_ROWS * NOUT) out[i] = bias[i % NOUT];
  const int j = i - B_ROWS * NOUT;
  if (j >= 0 && j < 16 * C_DIM)
    wb[j] = ((j >> 11) < NOUT) ? f2bf(W[(j >> 11) * C_DIM + (j & 2047)]) : (unsigned short)0;
  const int k = j - 16 * C_DIM;
  if (k >= 0 && k < C_DIM) scale[k] = __expf(-2.f * ls[k]) * LOG2E;
}

// --- main: 64x256 tile, 4 waves each 64 rows x 64 cols. No K-loop LDS/barriers.
// A frags identical across waves (L1 dedup); B frags wave-private (L2).
__global__ __launch_bounds__(256, 3) void rbf_main(
    const bf16x8* __restrict__ apk, const bf16x8* __restrict__ cbp,
    const __bf16* __restrict__ wb,
    const float* __restrict__ x2, const float* __restrict__ c2,
    const float* __restrict__ scale, float* __restrict__ out) {
  __shared__ __bf16 Ph[64 * 264];   // 33,792 B (+8 col pad)
  __shared__ float x2s[64];

  const int tid  = threadIdx.x;
  const int w    = tid >> 6;
  const int lane = tid & 63;
  const int q    = lane >> 4;
  const int l16  = lane & 15;
  const int bc   = blockIdx.x;        // 0..7   col block (256 cols)
  const int br   = blockIdx.y;        // 0..255 row block (64 rows)
  const int brow = br * 64;
  const int bcol = bc * 256;

  if (tid < 64) x2s[tid] = x2[brow + tid];
  __syncthreads();                    // before any vmem of the pipeline

  // A tiles: rg = br*4 + i, tile = rg*NKC + kc. Same for all 4 waves.
  const bf16x8* apA = apk + ((size_t)br * 4 * NKC) * 64 + lane;
  // B tiles: cg = bc*16 + w*4 + j, tile = kc*NCG + cg.
  const bf16x8* cbw = cbp + ((size_t)(bc * 16 + w * 4)) * 64 + lane;

  f32x4 acc[4][4] = {};
  bf16x8 afc[4], bfc[4], afn[4], bfn[4];
#pragma unroll
  for (int i = 0; i < 4; ++i) afc[i] = apA[(size_t)i * NKC * 64];
#pragma unroll
  for (int j = 0; j < 4; ++j) bfc[j] = cbw[(size_t)j * 64];

#pragma unroll 2
  for (int kc = 0; kc < NKC; ++kc) {
    const int kn = (kc + 1 < NKC) ? kc + 1 : NKC - 1;   // tail reload, L1 hit
#pragma unroll
    for (int i = 0; i < 4; ++i) afn[i] = apA[((size_t)i * NKC + kn) * 64];
#pragma unroll
    for (int j = 0; j < 4; ++j) bfn[j] = cbw[((size_t)kn * NCG + j) * 64];
#pragma unroll
    for (int i = 0; i < 4; ++i)
#pragma unroll
      for (int j = 0; j < 4; ++j)
        acc[i][j] = __builtin_amdgcn_mfma_f32_16x16x32_bf16(afc[i], bfc[j], acc[i][j], 0, 0, 0);
#pragma unroll
    for (int i = 0; i < 4; ++i) afc[i] = afn[i];
#pragma unroll
    for (int j = 0; j < 4; ++j) bfc[j] = bfn[j];
  }

  // epilogue 1: d2 -> phi -> Ph (bf16). C/D layout: col=lane&15, row=q*4+r.
#pragma unroll
  for (int i = 0; i < 4; ++i) {
    float xv[4];
#pragma unroll
    for (int r = 0; r < 4; ++r) xv[r] = x2s[i * 16 + q * 4 + r];
#pragma unroll
    for (int j = 0; j < 4; ++j) {
      const int cl = w * 64 + j * 16 + l16;          // 0..255
      const float c2v = c2[bcol + cl];
      const float sc = scale[bcol + cl];             // includes log2(e)
#pragma unroll
      for (int r = 0; r < 4; ++r) {
        const int rl = i * 16 + q * 4 + r;           // 0..63
        const float d2 = fmaxf(fmaf(-2.f, acc[i][j][r], xv[r] + c2v), 0.f);
        Ph[rl * 264 + cl] = (__bf16)__builtin_exp2f(-d2 * sc);
      }
    }
  }
  __syncthreads();

  // epilogue 2: out_tile(64x10) = Ph(64x256) @ Wb(16-row slice)^T, K=256.
  // wave w handles rows w*16..w*16+15.
  f32x4 oacc = {};
#pragma unroll
  for (int kk = 0; kk < 8; ++kk) {
    const bf16x8 bw = *(const bf16x8*)&wb[(size_t)l16 * C_DIM + bcol + kk * 32 + q * 8];
    const bf16x8 ap = *(const bf16x8*)&Ph[(w * 16 + l16) * 264 + kk * 32 + q * 8];
    oacc = __builtin_amdgcn_mfma_f32_16x16x32_bf16(ap, bw, oacc, 0, 0, 0);
  }
  if (l16 < NOUT) {
#pragma unroll
    for (int r = 0; r < 4; ++r) {
      const int grow = brow + w * 16 + q * 4 + r;
      atomicAdd(&out[grow * NOUT + l16], oacc[r]);
    }
  }
}

extern "C" void kernel_launch(void* const* d_in, const int* in_sizes, int n_in,
                              void* d_out, int out_size, void* d_ws, size_t ws_size,
                              hipStream_t stream) {
  const float* x    = (const float*)d_in[0];  // (16384,784)
  const float* cen  = (const float*)d_in[1];  // (2048,784)
  const float* ls   = (const float*)d_in[2];  // (2048,)
  const float* W    = (const float*)d_in[3];  // (10,2048)
  const float* bias = (const float*)d_in[4];  // (10,)
  float* out = (float*)d_out;                 // (16384,10)

  unsigned char* ws = (unsigned char*)d_ws;
  bf16x8* apk = (bf16x8*)(ws);                              // 1024*26 KB = 27,262,976
  bf16x8* cbp = (bf16x8*)(ws + 27262976);                   //  128*26 KB =  3,407,872
  unsigned short* wb = (unsigned short*)(ws + 30670848);    //  16*2048*2 =     65,536
  float* x2 = (float*)(ws + 30736384);                      // 16384*4
  float* c2 = (float*)(ws + 30801920);                      //  2048*4
  float* sc = (float*)(ws + 30810112);                      //  2048*4   (end 30,818,304)

  prep_pack<B_ROWS, 1><<<NRG / 4, 256, 0, stream>>>(x, apk, x2);
  prep_pack<C_DIM, 0><<<NCG / 4, 256, 0, stream>>>(cen, cbp, c2);
  prep_misc<<<(B_ROWS * NOUT + 16 * C_DIM + C_DIM + 255) / 256, 256, 0, stream>>>(
      ls, W, bias, sc, wb, out);
  rbf_main<<<dim3(8, 256), 256, 0, stream>>>(apk, cbp, (const __bf16*)wb, x2, c2, sc, out);
}

// Round 6
// 178.008 us; speedup vs baseline: 1.1399x; 1.1399x over previous
//
#include <hip/hip_runtime.h>

// RBF classifier: out = exp(-(||x-c||^2) * exp(-2*log_sigma)) @ W^T + b
// B=16384, D=784, C=2048, OUT=10. All fp32 in/out.
//
// R6 = R5 (zero-barrier fragment streaming) + XCD-locality grid swap
// (blockIdx.x = row-block => XCD = rb%8 keeps A slab L2-resident) +
// 4 waves/SIMD (launch_bounds(256,4); regs 60V+64A fit) + coalesced
// LDS-transpose pack kernels (R5's strided pack cost ~30us).

#define B_ROWS 16384
#define D_DIM  784
#define C_DIM  2048
#define NOUT   10
#define NKC    26             // k-chunks of 32 (K padded 784->832)
#define NCG    128            // B col-groups of 16
#define LOG2E  1.4426950408889634f

typedef __attribute__((ext_vector_type(8))) __bf16 bf16x8;
typedef __attribute__((ext_vector_type(4))) float  f32x4;
typedef __attribute__((ext_vector_type(4))) unsigned short ushort4v;

__device__ __forceinline__ unsigned short f2bf(float f) {
  union { float f; unsigned int u; } v; v.f = f;
  unsigned int u = v.u;
  return (unsigned short)((u + 0x7fffu + ((u >> 16) & 1u)) >> 16);  // RNE
}

// --- pack a (ROWS,784) fp32 matrix into MFMA fragment tiles via LDS
// transpose; one block per 16-row group. Phase 1: coalesced float4 read ->
// bf16 LDS (16 x 840, 16B-aligned rows). Phase 2: ds_read_b128 fragments,
// coalesced 1KB/wave global writes + squared norms (from bf16, consistent
// with the MFMA dot).
// A order: tile = g*NKC + kc. B order: tile = kc*(ROWS/16) + g.
template <int ROWS, int A_ORDER>
__global__ __launch_bounds__(256) void prep_pack(const float* __restrict__ src,
                                                 bf16x8* __restrict__ dst,
                                                 float* __restrict__ sq) {
  __shared__ unsigned short L[16 * 840];
  __shared__ float sqa[16];
  const int g = blockIdx.x;
  const int t = threadIdx.x;
  if (t < 16) sqa[t] = 0.f;
#pragma unroll
  for (int i = 0; i < 13; ++i) {            // 13*256 = 3328 = 16 rows * 208 ch
    const int chunk = t + 256 * i;
    const int row = chunk / 208;
    const int c4  = chunk % 208;
    const int k   = c4 * 4;
    ushort4v o = {0, 0, 0, 0};
    if (k + 4 <= D_DIM) {
      const float4 v = *(const float4*)(src + ((size_t)(g * 16 + row)) * D_DIM + k);
      o.x = f2bf(v.x); o.y = f2bf(v.y); o.z = f2bf(v.z); o.w = f2bf(v.w);
    }
    *(ushort4v*)&L[row * 840 + k] = o;
  }
  __syncthreads();
  const int w = t >> 6, lane = t & 63, q = lane >> 4, l16 = lane & 15;
  float part = 0.f;
  for (int i = 0; i < 7; ++i) {
    const int kc = w + 4 * i;
    if (kc < NKC) {
      union { bf16x8 v; __bf16 e[8]; } u;
      u.v = *(const bf16x8*)&L[l16 * 840 + kc * 32 + q * 8];
#pragma unroll
      for (int e = 0; e < 8; ++e) { const float x = (float)u.e[e]; part += x * x; }
      const size_t tile = A_ORDER ? ((size_t)g * NKC + kc)
                                  : ((size_t)kc * (ROWS / 16) + g);
      dst[tile * 64 + lane] = u.v;
    }
  }
  part += __shfl_down(part, 32);
  part += __shfl_down(part, 16);
  if (lane < 16) atomicAdd(&sqa[l16], part);
  __syncthreads();
  if (t < 16) sq[g * 16 + t] = sqa[t];
}

// fused tiny preps: out=bias | Wb bf16 (16,2048; rows 10..15 zero) | scale
// (pre-multiplied by log2(e) so epilogue uses exp2).
__global__ __launch_bounds__(256) void prep_misc(const float* __restrict__ ls,
                                                 const float* __restrict__ W,
                                                 const float* __restrict__ bias,
                                                 float* __restrict__ scale,
                                                 unsigned short* __restrict__ wb,
                                                 float* __restrict__ out) {
  const int i = blockIdx.x * 256 + threadIdx.x;
  if (i < B_ROWS * NOUT) out[i] = bias[i % NOUT];
  const int j = i - B_ROWS * NOUT;
  if (j >= 0 && j < 16 * C_DIM)
    wb[j] = ((j >> 11) < NOUT) ? f2bf(W[(j >> 11) * C_DIM + (j & 2047)]) : (unsigned short)0;
  const int k = j - 16 * C_DIM;
  if (k >= 0 && k < C_DIM) scale[k] = __expf(-2.f * ls[k]) * LOG2E;
}

// --- main: 64x256 tile, 4 waves each 64 rows x 64 cols. No K-loop LDS/barriers.
// blockIdx.x = row-block (256) so XCD = rb%8: per-XCD A slab ~3.3MB stays
// L2-resident; B col-slab 416KB per y. 4 waves/SIMD for latency coverage.
__global__ __launch_bounds__(256, 4) void rbf_main(
    const bf16x8* __restrict__ apk, const bf16x8* __restrict__ cbp,
    const __bf16* __restrict__ wb,
    const float* __restrict__ x2, const float* __restrict__ c2,
    const float* __restrict__ scale, float* __restrict__ out) {
  __shared__ __bf16 Ph[64 * 264];   // 33,792 B (+8 col pad)
  __shared__ float x2s[64];

  const int tid  = threadIdx.x;
  const int w    = tid >> 6;
  const int lane = tid & 63;
  const int q    = lane >> 4;
  const int l16  = lane & 15;
  const int br   = blockIdx.x;        // 0..255 row block (64 rows) -> XCD=br%8
  const int bc   = blockIdx.y;        // 0..7   col block (256 cols)
  const int brow = br * 64;
  const int bcol = bc * 256;

  if (tid < 64) x2s[tid] = x2[brow + tid];
  __syncthreads();                    // before any vmem of the pipeline

  // A tiles: rg = br*4 + i, tile = rg*NKC + kc. Same for all 4 waves.
  const bf16x8* apA = apk + ((size_t)br * 4 * NKC) * 64 + lane;
  // B tiles: cg = bc*16 + w*4 + j, tile = kc*NCG + cg.
  const bf16x8* cbw = cbp + ((size_t)(bc * 16 + w * 4)) * 64 + lane;

  f32x4 acc[4][4] = {};
  bf16x8 afc[4], bfc[4], afn[4], bfn[4];
#pragma unroll
  for (int i = 0; i < 4; ++i) afc[i] = apA[(size_t)i * NKC * 64];
#pragma unroll
  for (int j = 0; j < 4; ++j) bfc[j] = cbw[(size_t)j * 64];

#pragma unroll 2
  for (int kc = 0; kc < NKC; ++kc) {
    const int kn = (kc + 1 < NKC) ? kc + 1 : NKC - 1;   // tail reload, L1 hit
#pragma unroll
    for (int i = 0; i < 4; ++i) afn[i] = apA[((size_t)i * NKC + kn) * 64];
#pragma unroll
    for (int j = 0; j < 4; ++j) bfn[j] = cbw[((size_t)kn * NCG + j) * 64];
#pragma unroll
    for (int i = 0; i < 4; ++i)
#pragma unroll
      for (int j = 0; j < 4; ++j)
        acc[i][j] = __builtin_amdgcn_mfma_f32_16x16x32_bf16(afc[i], bfc[j], acc[i][j], 0, 0, 0);
#pragma unroll
    for (int i = 0; i < 4; ++i) afc[i] = afn[i];
#pragma unroll
    for (int j = 0; j < 4; ++j) bfc[j] = bfn[j];
  }

  // epilogue 1: d2 -> phi -> Ph (bf16). C/D layout: col=lane&15, row=q*4+r.
#pragma unroll
  for (int i = 0; i < 4; ++i) {
    float xv[4];
#pragma unroll
    for (int r = 0; r < 4; ++r) xv[r] = x2s[i * 16 + q * 4 + r];
#pragma unroll
    for (int j = 0; j < 4; ++j) {
      const int cl = w * 64 + j * 16 + l16;          // 0..255
      const float c2v = c2[bcol + cl];
      const float sc = scale[bcol + cl];             // includes log2(e)
#pragma unroll
      for (int r = 0; r < 4; ++r) {
        const int rl = i * 16 + q * 4 + r;           // 0..63
        const float d2 = fmaxf(fmaf(-2.f, acc[i][j][r], xv[r] + c2v), 0.f);
        Ph[rl * 264 + cl] = (__bf16)__builtin_exp2f(-d2 * sc);
      }
    }
  }
  __syncthreads();

  // epilogue 2: out_tile(64x10) = Ph(64x256) @ Wb(16-row slice)^T, K=256.
  // wave w handles rows w*16..w*16+15.
  f32x4 oacc = {};
#pragma unroll
  for (int kk = 0; kk < 8; ++kk) {
    const bf16x8 bw = *(const bf16x8*)&wb[(size_t)l16 * C_DIM + bcol + kk * 32 + q * 8];
    const bf16x8 ap = *(const bf16x8*)&Ph[(w * 16 + l16) * 264 + kk * 32 + q * 8];
    oacc = __builtin_amdgcn_mfma_f32_16x16x32_bf16(ap, bw, oacc, 0, 0, 0);
  }
  if (l16 < NOUT) {
#pragma unroll
    for (int r = 0; r < 4; ++r) {
      const int grow = brow + w * 16 + q * 4 + r;
      atomicAdd(&out[grow * NOUT + l16], oacc[r]);
    }
  }
}

extern "C" void kernel_launch(void* const* d_in, const int* in_sizes, int n_in,
                              void* d_out, int out_size, void* d_ws, size_t ws_size,
                              hipStream_t stream) {
  const float* x    = (const float*)d_in[0];  // (16384,784)
  const float* cen  = (const float*)d_in[1];  // (2048,784)
  const float* ls   = (const float*)d_in[2];  // (2048,)
  const float* W    = (const float*)d_in[3];  // (10,2048)
  const float* bias = (const float*)d_in[4];  // (10,)
  float* out = (float*)d_out;                 // (16384,10)

  unsigned char* ws = (unsigned char*)d_ws;
  bf16x8* apk = (bf16x8*)(ws);                              // 1024*26 KB = 27,262,976
  bf16x8* cbp = (bf16x8*)(ws + 27262976);                   //  128*26 KB =  3,407,872
  unsigned short* wb = (unsigned short*)(ws + 30670848);    //  16*2048*2 =     65,536
  float* x2 = (float*)(ws + 30736384);                      // 16384*4
  float* c2 = (float*)(ws + 30801920);                      //  2048*4
  float* sc = (float*)(ws + 30810112);                      //  2048*4   (end 30,818,304)

  prep_pack<B_ROWS, 1><<<B_ROWS / 16, 256, 0, stream>>>(x, apk, x2);
  prep_pack<C_DIM, 0><<<C_DIM / 16, 256, 0, stream>>>(cen, cbp, c2);
  prep_misc<<<(B_ROWS * NOUT + 16 * C_DIM + C_DIM + 255) / 256, 256, 0, stream>>>(
      ls, W, bias, sc, wb, out);
  rbf_main<<<dim3(256, 8), 256, 0, stream>>>(apk, cbp, (const __bf16*)wb, x2, c2, sc, out);
}